// Round 10
// baseline (316.064 us; speedup 1.0000x reference)
//
#include <hip/hip_runtime.h>
#include <math.h>

// Problem constants (x: [8192, 512] fp32, K=5, eps=1e-8, scalar fp32 loss)
#define NROWS 8192
#define DIM   512
#define KNN   5
#define EPSV  1e-8f

// GEMM tiling (r4-exact dots body): 128x128 tile, BK=32, 4 waves (2x2), each
// wave 4x4 of 16x16x32 MFMA, single LDS buffer, 2 barriers/K-step.
// Round-10: fused persistent kernel with a HAND-ROLLED grid barrier.
//  - r9 lesson: hipLaunchCooperativeKernel silently fails inside the
//    harness's graph capture (out never written, absmax == |ref|). A spin
//    barrier is an ordinary launch -> graph-safe.
//  - Deadlock safety by capacity: 256 blocks x 256 thr, <=156 unified regs,
//    16.2KB LDS -> >=2 blocks/CU capacity -> all 256 co-resident even under
//    worst-case packing (needs only 128 CUs). No scheduler assumption beyond
//    "a block starts when resources are free".
//  - Cross-XCD coherence: agent-scope atomics carry release/acquire; the
//    counter RMW chain (ACQ_REL) + gen release-store + gen acquire-load
//    make all blocks' non-atomic stores (xnh, M3, partials) visible.
#define BM 128
#define BN 128
#define BK 32
#define NT64 (NROWS / 64)      // 128 64-col tiles per row
#define NKS (DIM / BK)         // 16 K-steps
#define NWORK 2080             // 64*65/2 upper-triangular work items (= 8*260)
#define NBLK 256               // persistent blocks (capacity-guaranteed resident)

typedef __attribute__((ext_vector_type(8))) _Float16 f16x8;
typedef __attribute__((ext_vector_type(4))) float    f32x4;

// async global->LDS, 16B per lane (LDS dest must be wave-uniform base + lane*16)
__device__ __forceinline__ void gload16(const _Float16* g, _Float16* l) {
    __builtin_amdgcn_global_load_lds(
        (const __attribute__((address_space(1))) void*)g,
        (__attribute__((address_space(3))) void*)l, 16, 0, 0);
}

__device__ __forceinline__ void cmpswap(float& a, float& b) {
    const float hi = fmaxf(a, b), lo = fminf(a, b);
    a = hi; b = lo;
}

// merge two sorted-descending 5-lists -> top-5 (into a).
__device__ __forceinline__ void merge5(float a[KNN], const float b[KNN]) {
    const float c0 = fmaxf(a[0], b[0]);
    const float c1 = fmaxf(fmaxf(a[1], b[1]), fminf(a[0], b[0]));
    const float c2 = fmaxf(fmaxf(a[2], b[2]),
                           fmaxf(fminf(a[0], b[1]), fminf(a[1], b[0])));
    const float c3 = fmaxf(fmaxf(a[3], b[3]),
                           fmaxf(fminf(a[0], b[2]),
                                 fmaxf(fminf(a[1], b[1]), fminf(a[2], b[0]))));
    const float c4 = fmaxf(fmaxf(a[4], b[4]),
                           fmaxf(fmaxf(fminf(a[0], b[3]), fminf(a[1], b[2])),
                                 fmaxf(fminf(a[2], b[1]), fminf(a[3], b[0]))));
    a[0] = c0; a[1] = c1; a[2] = c2; a[3] = c3; a[4] = c4;
}

// sense-reversing grid barrier, agent scope. Release sequence on cnt makes
// every block's prior (non-atomic) stores visible to every acquirer of gen.
__device__ __forceinline__ void grid_barrier(int* cnt, int* gen) {
    __syncthreads();
    if (threadIdx.x == 0) {
        const int g = __hip_atomic_load(gen, __ATOMIC_RELAXED,
                                        __HIP_MEMORY_SCOPE_AGENT);
        const int prev = __hip_atomic_fetch_add(cnt, 1, __ATOMIC_ACQ_REL,
                                                __HIP_MEMORY_SCOPE_AGENT);
        if (prev == NBLK - 1) {
            __hip_atomic_store(cnt, 0, __ATOMIC_RELAXED,
                               __HIP_MEMORY_SCOPE_AGENT);
            __hip_atomic_store(gen, g + 1, __ATOMIC_RELEASE,
                               __HIP_MEMORY_SCOPE_AGENT);
        } else {
            while (__hip_atomic_load(gen, __ATOMIC_ACQUIRE,
                                     __HIP_MEMORY_SCOPE_AGENT) == g) {
                __builtin_amdgcn_s_sleep(8);
            }
        }
    }
    __syncthreads();
}

// ---------------------------------------------------------------------------
// ONE persistent kernel, 256 blocks x 256 threads.
// A: normalize (8 rows/wave)                       -> xnh
// B: dots+top3, grid-strided r2 XCD work map       -> M3   (r4-exact body)
// C: exact top-5 + per-block loss sum (8 rows/wave)-> partials[256]
// D: block 0 reduces partials                      -> out
// ---------------------------------------------------------------------------
__global__ __launch_bounds__(256) void fused_kernel(const float* __restrict__ x,
                                                    _Float16* __restrict__ xnh,
                                                    float* __restrict__ M3,
                                                    float* __restrict__ partials,
                                                    int* __restrict__ syncv,
                                                    float* __restrict__ out) {
    const int tid  = threadIdx.x;
    const int lane = tid & 63;
    const int wv   = tid >> 6;
    const int bid  = blockIdx.x;

    __shared__ __align__(16) _Float16 As[BM * BK];   // 8 KB
    __shared__ __align__(16) _Float16 Bs[BN * BK];   // 8 KB
    __shared__ float red[4];

    int* cnt = syncv;
    int* gen = syncv + 1;

    // ======== Phase A: row-normalize x -> xn (f16). 8 rows per wave. ========
    #pragma unroll
    for (int t = 0; t < 8; ++t) {
        const int row = (bid * 4 + wv) + 1024 * t;
        const float4* xr = (const float4*)(x + (size_t)row * DIM) + lane * 2;
        const float4 a = xr[0];
        const float4 b = xr[1];
        float s = a.x * a.x + a.y * a.y + a.z * a.z + a.w * a.w
                + b.x * b.x + b.y * b.y + b.z * b.z + b.w * b.w;
        #pragma unroll
        for (int off = 1; off < 64; off <<= 1) s += __shfl_xor(s, off, 64);
        const float inv = 1.0f / sqrtf(s);
        const f16x8 h = { (_Float16)(a.x * inv), (_Float16)(a.y * inv),
                          (_Float16)(a.z * inv), (_Float16)(a.w * inv),
                          (_Float16)(b.x * inv), (_Float16)(b.y * inv),
                          (_Float16)(b.z * inv), (_Float16)(b.w * inv) };
        *(f16x8*)(xnh + (size_t)row * DIM + lane * 8) = h;
    }

    grid_barrier(cnt, gen);

    // ======== Phase B: triangular Gram tiles + per-64-col top-3. ========
    // XCD (bid&7) owns work [xcd*260, (xcd+1)*260); its 32 blocks stride by
    // 32 (8-9 items each) -> the r2-proven L2 super-tile locality holds.
    {
        const int xcd = bid & 7;
        const int q   = bid >> 3;                  // 0..31
        const int wm     = wv >> 1;
        const int wn     = wv & 1;
        const int m_lane = lane & 15;
        const int quad   = lane >> 4;
        const int rowlocal = (m_lane >> 2) * 16 + quad * 4 + (m_lane & 3);
        const int rchunk   = (quad ^ ((m_lane >> 1) & 3)) * 8;
        const int s0 = tid, s1 = tid + 256;
        const int r0g = s0 >> 2, r1g = s1 >> 2;
        const int kg0 = (s0 & 3) ^ ((s0 >> 3) & 3);
        const int kg1 = (s1 & 3) ^ ((s1 >> 3) & 3);

        for (int w = xcd * 260 + q; w < xcd * 260 + 260; w += 32) {
            // decode global work index w -> (I,J) over super-tiles (r2 map)
            int I, J;
            {
                int rem = w, found = 0;
                for (int SI = 0; SI < 8 && !found; ++SI) {
                    for (int SJ = SI; SJ < 8 && !found; ++SJ) {
                        const int sz = (SI == SJ) ? 36 : 64;
                        if (rem < sz) {
                            if (SI == SJ) {
                                int i = 0, r2 = rem;
                                while (r2 >= 8 - i) { r2 -= 8 - i; ++i; }
                                I = SI * 8 + i;
                                J = SJ * 8 + i + r2;
                            } else {
                                I = SI * 8 + (rem >> 3);
                                J = SJ * 8 + (rem & 7);
                            }
                            found = 1;
                        } else {
                            rem -= sz;
                        }
                    }
                }
            }

            const int i0 = I * BM;
            const int j0 = J * BN;
            const int myrow = i0 + wm * 64 + rowlocal;
            const _Float16* gA0 = xnh + (size_t)(i0 + r0g) * DIM + kg0 * 8;
            const _Float16* gA1 = xnh + (size_t)(i0 + r1g) * DIM + kg1 * 8;
            const _Float16* gB0 = xnh + (size_t)(j0 + r0g) * DIM + kg0 * 8;
            const _Float16* gB1 = xnh + (size_t)(j0 + r1g) * DIM + kg1 * 8;

            f32x4 acc[4][4];
            #pragma unroll
            for (int m = 0; m < 4; ++m)
                #pragma unroll
                for (int n = 0; n < 4; ++n)
                    acc[m][n] = (f32x4){0.f, 0.f, 0.f, 0.f};

            for (int ks = 0; ks < NKS; ++ks) {
                const int k0 = ks * BK;
                gload16(gA0 + k0, As + s0 * 8);
                gload16(gA1 + k0, As + s1 * 8);
                gload16(gB0 + k0, Bs + s0 * 8);
                gload16(gB1 + k0, Bs + s1 * 8);
                __syncthreads();

                f16x8 af[4], bf[4];
                #pragma unroll
                for (int m = 0; m < 4; ++m)
                    af[m] = *(const f16x8*)(As + (wm * 64 + m * 16 + m_lane) * BK + rchunk);
                #pragma unroll
                for (int n = 0; n < 4; ++n)
                    bf[n] = *(const f16x8*)(Bs + (wn * 64 + n * 16 + m_lane) * BK + rchunk);
                #pragma unroll
                for (int m = 0; m < 4; ++m)
                    #pragma unroll
                    for (int n = 0; n < 4; ++n)
                        acc[m][n] = __builtin_amdgcn_mfma_f32_16x16x32_f16(af[m], bf[n], acc[m][n], 0, 0, 0);
                __syncthreads();
            }

            // diagonal mask: self-dot only when I==J && wm==wn && m==n.
            const bool diag = (I == J) && (wm == wn);
            #pragma unroll
            for (int m = 0; m < 4; ++m)
                #pragma unroll
                for (int i = 0; i < 4; ++i)
                    acc[m][m][i] = (diag && (quad * 4 + i) == m_lane) ? -2.f : acc[m][m][i];

            // row-side: per (m,i), top-3 of this row's 64 cols (butterfly)
            float g1 = -2.f, g2 = -2.f, g3 = -2.f;
            #pragma unroll
            for (int m = 0; m < 4; ++m) {
                #pragma unroll
                for (int i = 0; i < 4; ++i) {
                    float v0 = acc[m][0][i], v1 = acc[m][1][i];
                    float v2 = acc[m][2][i], v3 = acc[m][3][i];
                    cmpswap(v0, v1); cmpswap(v2, v3);
                    cmpswap(v0, v2); cmpswap(v1, v3);
                    cmpswap(v1, v2);
                    float a1 = v0, a2 = v1, a3 = v2;
                    #pragma unroll
                    for (int d = 1; d < 16; d <<= 1) {
                        const float b1 = __shfl_xor(a1, d, 64);
                        const float b2 = __shfl_xor(a2, d, 64);
                        const float b3 = __shfl_xor(a3, d, 64);
                        const float n1 = fmaxf(a1, b1);
                        const float n2 = fmaxf(fminf(a1, b1), fmaxf(a2, b2));
                        const float n3 = fmaxf(fmaxf(a3, b3),
                                               fmaxf(fminf(a1, b2), fminf(a2, b1)));
                        a1 = n1; a2 = n2; a3 = n3;
                    }
                    const bool own = (m_lane == m * 4 + i);
                    g1 = own ? a1 : g1; g2 = own ? a2 : g2; g3 = own ? a3 : g3;
                }
            }
            {
                float* p = M3 + ((size_t)myrow * NT64 + (J * 2 + wn)) * 3;
                p[0] = g1; p[1] = g2; p[2] = g3;
            }

            // col-side (I != J): per n, top-3 of this col's 64 rows
            if (I != J) {
                #pragma unroll
                for (int n = 0; n < 4; ++n) {
                    float c1 = -2.f, c2 = -2.f, c3 = -2.f;
                    #pragma unroll
                    for (int m = 0; m < 4; ++m)
                        #pragma unroll
                        for (int i = 0; i < 4; ++i) {
                            const float v  = acc[m][n][i];
                            const float u1 = fminf(c1, v);
                            c1 = fmaxf(c1, v);
                            const float u2 = fminf(c2, u1);
                            c2 = fmaxf(c2, u1);
                            c3 = fmaxf(c3, u2);
                        }
                    #pragma unroll
                    for (int d = 16; d < 64; d <<= 1) {
                        const float b1 = __shfl_xor(c1, d, 64);
                        const float b2 = __shfl_xor(c2, d, 64);
                        const float b3 = __shfl_xor(c3, d, 64);
                        const float n2 = fmaxf(fminf(c1, b1), fmaxf(c2, b2));
                        const float n3 = fmaxf(fmaxf(c3, b3),
                                               fmaxf(fminf(c1, b2), fminf(c2, b1)));
                        c1 = fmaxf(c1, b1); c2 = n2; c3 = n3;
                    }
                    if (quad == 0) {
                        const int col = j0 + wn * 64 + n * 16 + m_lane;
                        float* p = M3 + ((size_t)col * NT64 + (I * 2 + wm)) * 3;
                        p[0] = c1; p[1] = c2; p[2] = c3;
                    }
                }
            }
        }
    }

    grid_barrier(cnt, gen);

    // ======== Phase C: exact top-5 per row + per-block loss partial. ========
    {
        float wsum = 0.f;
        #pragma unroll
        for (int t = 0; t < 8; ++t) {
            const int row = (bid * 4 + wv) + 1024 * t;
            const float* p = M3 + (size_t)row * NT64 * 3 + lane * 6;
            float a[3], b[3];
            a[0] = p[0]; a[1] = p[1]; a[2] = p[2];
            b[0] = p[3]; b[1] = p[4]; b[2] = p[5];

            float tk[KNN];
            {
                float c[KNN] = { a[0], a[1], a[2], -2.f, -2.f };
                const float bb[KNN] = { b[0], b[1], b[2], -2.f, -2.f };
                merge5(c, bb);
                #pragma unroll
                for (int d = 1; d < 64; d <<= 1) {
                    float o[KNN];
                    #pragma unroll
                    for (int k = 0; k < KNN; ++k) o[k] = __shfl_xor(c[k], d, 64);
                    merge5(c, o);
                }
                #pragma unroll
                for (int k = 0; k < KNN; ++k) tk[k] = c[k];
            }

            const unsigned long long ba  = __ballot(a[2] >= tk[4]);
            const unsigned long long bb_ = __ballot(b[2] >= tk[4]);
            if (ba | bb_) {
                const bool fA = (ba >> lane) & 1ull, fB = (bb_ >> lane) & 1ull;
                float c[KNN] = { fA ? -2.f : a[0], fA ? -2.f : a[1],
                                 fA ? -2.f : a[2], -2.f, -2.f };
                const float b5[KNN] = { fB ? -2.f : b[0], fB ? -2.f : b[1],
                                        fB ? -2.f : b[2], -2.f, -2.f };
                merge5(c, b5);
                #pragma unroll
                for (int d = 1; d < 64; d <<= 1) {
                    float o[KNN];
                    #pragma unroll
                    for (int k = 0; k < KNN; ++k) o[k] = __shfl_xor(c[k], d, 64);
                    merge5(c, o);
                }
                #pragma unroll
                for (int k = 0; k < KNN; ++k) tk[k] = c[k];

                unsigned long long fl[2] = { ba, bb_ };
                #pragma unroll
                for (int h = 0; h < 2; ++h) {
                    unsigned long long m = fl[h];
                    while (m) {
                        const int l = __ffsll((long long)m) - 1;
                        m &= m - 1;
                        const int jt2 = 2 * l + h;
                        const int col = jt2 * 64 + lane;
                        const _Float16* rp = xnh + (size_t)row * DIM;
                        const _Float16* cp = xnh + (size_t)col * DIM;
                        float d = 0.f;
                        for (int k8 = 0; k8 < DIM / 8; ++k8) {
                            const f16x8 rv = *(const f16x8*)(rp + k8 * 8);
                            const f16x8 cv = *(const f16x8*)(cp + k8 * 8);
                            #pragma unroll
                            for (int e = 0; e < 8; ++e)
                                d += (float)rv[e] * (float)cv[e];
                        }
                        if (col == row) d = -2.f;
                        float c2[KNN] = { d, -2.f, -2.f, -2.f, -2.f };
                        #pragma unroll
                        for (int dd = 1; dd < 64; dd <<= 1) {
                            float o[KNN];
                            #pragma unroll
                            for (int k = 0; k < KNN; ++k) o[k] = __shfl_xor(c2[k], dd, 64);
                            merge5(c2, o);
                        }
                        merge5(tk, c2);
                    }
                }
            }

            float s = 0.f;
            #pragma unroll
            for (int k = 0; k < KNN; ++k) s += sqrtf(fmaxf(2.f - 2.f * tk[k], 0.f));
            wsum += logf(s * (1.f / KNN) + EPSV);
        }

        if (lane == 0) red[wv] = wsum;
        __syncthreads();
        if (tid == 0)
            partials[bid] = red[0] + red[1] + red[2] + red[3];
    }

    grid_barrier(cnt, gen);

    // ======== Phase D: block 0 reduces the 256 partials -> loss. ========
    if (bid == 0) {
        float s = partials[tid];
        #pragma unroll
        for (int off = 1; off < 64; off <<= 1) s += __shfl_xor(s, off, 64);
        __syncthreads();                 // red[] reuse after phase C
        if (lane == 0) red[wv] = s;
        __syncthreads();
        if (tid == 0)
            *out = -(red[0] + red[1] + red[2] + red[3]) / (float)NROWS;
    }
}

// ---------------------------------------------------------------------------
extern "C" void kernel_launch(void* const* d_in, const int* in_sizes, int n_in,
                              void* d_out, int out_size, void* d_ws, size_t ws_size,
                              hipStream_t stream) {
    const float* x = (const float*)d_in[0];
    float* out = (float*)d_out;
    char* ws = (char*)d_ws;

    _Float16* xnh = (_Float16*)ws;                                     // 8 MB
    float* M3 = (float*)(ws + (size_t)NROWS * DIM * sizeof(_Float16)); // 12.6 MB
    float* partials = M3 + (size_t)NROWS * NT64 * 3;                   // 1 KB
    int* syncv = (int*)(partials + NBLK);                              // 8 B

    // zero the barrier state each replay (captured stream op, graph-legal:
    // the harness itself enqueues hipMemsetAsync during capture)
    hipMemsetAsync(syncv, 0, 2 * sizeof(int), stream);
    fused_kernel<<<NBLK, 256, 0, stream>>>(x, xnh, M3, partials, syncv, out);
}

// Round 11
// 185.470 us; speedup vs baseline: 1.7041x; 1.7041x over previous
//
#include <hip/hip_runtime.h>
#include <math.h>

// Problem constants (x: [8192, 512] fp32, K=5, eps=1e-8, scalar fp32 loss)
#define NROWS 8192
#define DIM   512
#define KNN   5
#define EPSV  1e-8f

// GEMM tiling (r4-exact, best verified: 144.7us total): 128x128 block tile,
// BK=32, 4 waves (2x2), each wave 4x4 of 16x16x32 MFMA, single LDS buffer,
// 2 barriers/K-step.
// Round-11: revert r10's full fusion (occupancy 11.9% -> dots lost its
// inter-block TLP, 316us). Keep the 4-kernel structure but merge
// select+reduce via the threadfence last-block-done pattern (no grid
// barrier, no co-residency requirement) -> one fewer launch boundary.
#define BM 128
#define BN 128
#define BK 32
#define NT64 (NROWS / 64)      // 128 64-col tiles per row
#define NKS (DIM / BK)         // 16 K-steps
#define NWORK 2080             // 64*65/2 upper-triangular work blocks (= 8*260)
#define NSEL (NROWS / 4)       // select blocks (4 waves, 1 row/wave) = 2048

typedef __attribute__((ext_vector_type(8))) _Float16 f16x8;
typedef __attribute__((ext_vector_type(4))) float    f32x4;

// async global->LDS, 16B per lane (LDS dest must be wave-uniform base + lane*16)
__device__ __forceinline__ void gload16(const _Float16* g, _Float16* l) {
    __builtin_amdgcn_global_load_lds(
        (const __attribute__((address_space(1))) void*)g,
        (__attribute__((address_space(3))) void*)l, 16, 0, 0);
}

__device__ __forceinline__ void cmpswap(float& a, float& b) {
    const float hi = fmaxf(a, b), lo = fminf(a, b);
    a = hi; b = lo;
}

// merge two sorted-descending 5-lists -> top-5 (into a).
__device__ __forceinline__ void merge5(float a[KNN], const float b[KNN]) {
    const float c0 = fmaxf(a[0], b[0]);
    const float c1 = fmaxf(fmaxf(a[1], b[1]), fminf(a[0], b[0]));
    const float c2 = fmaxf(fmaxf(a[2], b[2]),
                           fmaxf(fminf(a[0], b[1]), fminf(a[1], b[0])));
    const float c3 = fmaxf(fmaxf(a[3], b[3]),
                           fmaxf(fminf(a[0], b[2]),
                                 fmaxf(fminf(a[1], b[1]), fminf(a[2], b[0]))));
    const float c4 = fmaxf(fmaxf(a[4], b[4]),
                           fmaxf(fmaxf(fminf(a[0], b[3]), fminf(a[1], b[2])),
                                 fmaxf(fminf(a[2], b[1]), fminf(a[3], b[0]))));
    a[0] = c0; a[1] = c1; a[2] = c2; a[3] = c3; a[4] = c4;
}

// ---------------------------------------------------------------------------
// Kernel 1: row-normalize x (fp32) -> xn (f16). One WAVE per row, 16B stores.
// ---------------------------------------------------------------------------
__global__ __launch_bounds__(256) void norm_kernel(const float* __restrict__ x,
                                                   _Float16* __restrict__ xnh) {
    const int wv = threadIdx.x >> 6, lane = threadIdx.x & 63;
    const int row = blockIdx.x * 4 + wv;
    const float4* xr = (const float4*)(x + (size_t)row * DIM) + lane * 2;
    const float4 a = xr[0];
    const float4 b = xr[1];
    float s = a.x * a.x + a.y * a.y + a.z * a.z + a.w * a.w
            + b.x * b.x + b.y * b.y + b.z * b.z + b.w * b.w;
    #pragma unroll
    for (int off = 1; off < 64; off <<= 1) s += __shfl_xor(s, off, 64);
    const float inv = 1.0f / sqrtf(s);
    const f16x8 h = { (_Float16)(a.x * inv), (_Float16)(a.y * inv),
                      (_Float16)(a.z * inv), (_Float16)(a.w * inv),
                      (_Float16)(b.x * inv), (_Float16)(b.y * inv),
                      (_Float16)(b.z * inv), (_Float16)(b.w * inv) };
    *(f16x8*)(xnh + (size_t)row * DIM + lane * 8) = h;
}

// ---------------------------------------------------------------------------
// Kernel 2: TRIANGULAR Gram-tile GEMM + per-(row, 64-col-tile) top-3.
// r4-EXACT (best verified). Session ledger for this kernel:
//  - BK=32 single-buffer 2-barrier loop; 2080-block launch for TLP.
//    Sync-family all null at ~84us: syncthreads-dbuf (r1), BK=64 (r3),
//    8-wave (r5), counted-vmcnt depth-1 (r7), depth-2/3-buf (r8).
//    Persistent/fused (r10) regressed 2x: dots NEEDS inter-block TLP.
//  - Direct-from-global fragments (r6) 2x slower: request-bound scatter.
//  - XOR chunk swizzle (r1: conflicts 4.26M->0), XCD super-tile map
//    (r2: FETCH 33->23MB, -16us) both proven, kept.
// ---------------------------------------------------------------------------
__global__ __launch_bounds__(256) void dots_top3_kernel(const _Float16* __restrict__ xnh,
                                                        float* __restrict__ M3) {
    // ---- work-index decode: launch b -> XCD-contiguous work item w -> (I,J)
    int I, J;
    {
        int rem = (int)(blockIdx.x & 7) * (NWORK / 8) + (int)(blockIdx.x >> 3);
        int found = 0;
        for (int SI = 0; SI < 8 && !found; ++SI) {
            for (int SJ = SI; SJ < 8 && !found; ++SJ) {
                const int sz = (SI == SJ) ? 36 : 64;
                if (rem < sz) {
                    if (SI == SJ) {
                        int i = 0, r2 = rem;
                        while (r2 >= 8 - i) { r2 -= 8 - i; ++i; }
                        I = SI * 8 + i;
                        J = SJ * 8 + i + r2;
                    } else {
                        I = SI * 8 + (rem >> 3);
                        J = SJ * 8 + (rem & 7);
                    }
                    found = 1;
                } else {
                    rem -= sz;
                }
            }
        }
    }

    __shared__ __align__(16) _Float16 As[BM * BK];   // 8 KB
    __shared__ __align__(16) _Float16 Bs[BN * BK];   // 8 KB

    const int tid    = threadIdx.x;
    const int lane   = tid & 63;
    const int wv     = tid >> 6;
    const int wm     = wv >> 1;          // wave row half (0..1)
    const int wn     = wv & 1;           // wave col half (0..1)
    const int m_lane = lane & 15;        // MFMA: m (A) / n (B) / col (C)
    const int quad   = lane >> 4;        // MFMA: k-chunk (A,B) / row-group (C)

    const int i0 = I * BM;
    const int j0 = J * BN;

    // lane (quad, m_lane) owns row rowlocal (its (m,i) = (m_lane>>2, m_lane&3))
    const int rowlocal = (m_lane >> 2) * 16 + quad * 4 + (m_lane & 3);
    const int myrow    = i0 + wm * 64 + rowlocal;

    // fragment-read chunk swizzle: (row>>1)&3 == (m_lane>>1)&3 for every m, wm
    const int rchunk = (quad ^ ((m_lane >> 1) & 3)) * 8;

    f32x4 acc[4][4];
    #pragma unroll
    for (int m = 0; m < 4; ++m)
        #pragma unroll
        for (int n = 0; n < 4; ++n)
            acc[m][n] = (f32x4){0.f, 0.f, 0.f, 0.f};

    for (int ks = 0; ks < NKS; ++ks) {
        const int k0 = ks * BK;
        // LDS slot s (row r, chunk kk) receives global chunk kk ^ ((r>>1)&3)
        // (involution; fragment read applies the same XOR via rchunk).
        #pragma unroll
        for (int q = 0; q < 2; ++q) {
            const int s  = tid + q * 256;
            const int r  = s >> 2;
            const int kg = (s & 3) ^ ((s >> 3) & 3);
            gload16(xnh + (size_t)(i0 + r) * DIM + k0 + kg * 8, As + s * 8);
            gload16(xnh + (size_t)(j0 + r) * DIM + k0 + kg * 8, Bs + s * 8);
        }
        __syncthreads();

        f16x8 af[4], bf[4];
        #pragma unroll
        for (int m = 0; m < 4; ++m)
            af[m] = *(const f16x8*)(As + (wm * 64 + m * 16 + m_lane) * BK + rchunk);
        #pragma unroll
        for (int n = 0; n < 4; ++n)
            bf[n] = *(const f16x8*)(Bs + (wn * 64 + n * 16 + m_lane) * BK + rchunk);
        #pragma unroll
        for (int m = 0; m < 4; ++m)
            #pragma unroll
            for (int n = 0; n < 4; ++n)
                acc[m][n] = __builtin_amdgcn_mfma_f32_16x16x32_f16(af[m], bf[n], acc[m][n], 0, 0, 0);
        __syncthreads();
    }

    // diagonal mask: self-dot only when I==J && wm==wn && m==n.
    const bool diag = (I == J) && (wm == wn);
    #pragma unroll
    for (int m = 0; m < 4; ++m)
        #pragma unroll
        for (int i = 0; i < 4; ++i)
            acc[m][m][i] = (diag && (quad * 4 + i) == m_lane) ? -2.f : acc[m][m][i];

    // ---- row-side: per (m,i), top-3 of this row's 64 cols (butterfly) ----
    float g1 = -2.f, g2 = -2.f, g3 = -2.f;
    #pragma unroll
    for (int m = 0; m < 4; ++m) {
        #pragma unroll
        for (int i = 0; i < 4; ++i) {
            float v0 = acc[m][0][i], v1 = acc[m][1][i];
            float v2 = acc[m][2][i], v3 = acc[m][3][i];
            cmpswap(v0, v1); cmpswap(v2, v3);
            cmpswap(v0, v2); cmpswap(v1, v3);
            cmpswap(v1, v2);                     // v0>=v1>=v2 (>=v3, dropped)
            float a1 = v0, a2 = v1, a3 = v2;
            #pragma unroll
            for (int d = 1; d < 16; d <<= 1) {
                const float b1 = __shfl_xor(a1, d, 64);
                const float b2 = __shfl_xor(a2, d, 64);
                const float b3 = __shfl_xor(a3, d, 64);
                const float n1 = fmaxf(a1, b1);
                const float n2 = fmaxf(fminf(a1, b1), fmaxf(a2, b2));
                const float n3 = fmaxf(fmaxf(a3, b3),
                                       fmaxf(fminf(a1, b2), fminf(a2, b1)));
                a1 = n1; a2 = n2; a3 = n3;
            }
            const bool own = (m_lane == m * 4 + i);
            g1 = own ? a1 : g1; g2 = own ? a2 : g2; g3 = own ? a3 : g3;
        }
    }
    {
        float* p = M3 + ((size_t)myrow * NT64 + (J * 2 + wn)) * 3;
        p[0] = g1; p[1] = g2; p[2] = g3;
    }

    // ---- col-side (I != J): per n, top-3 of this col's 64 rows ----
    if (I != J) {
        #pragma unroll
        for (int n = 0; n < 4; ++n) {
            float c1 = -2.f, c2 = -2.f, c3 = -2.f;
            #pragma unroll
            for (int m = 0; m < 4; ++m)
                #pragma unroll
                for (int i = 0; i < 4; ++i) {
                    const float v  = acc[m][n][i];
                    const float u1 = fminf(c1, v);
                    c1 = fmaxf(c1, v);
                    const float u2 = fminf(c2, u1);
                    c2 = fmaxf(c2, u1);
                    c3 = fmaxf(c3, u2);
                }
            #pragma unroll
            for (int d = 16; d < 64; d <<= 1) {
                const float b1 = __shfl_xor(c1, d, 64);
                const float b2 = __shfl_xor(c2, d, 64);
                const float b3 = __shfl_xor(c3, d, 64);
                const float n2 = fmaxf(fminf(c1, b1), fmaxf(c2, b2));
                const float n3 = fmaxf(fmaxf(c3, b3),
                                       fmaxf(fminf(c1, b2), fminf(c2, b1)));
                c1 = fmaxf(c1, b1); c2 = n2; c3 = n3;
            }
            if (quad == 0) {
                const int col = j0 + wn * 64 + n * 16 + m_lane;
                float* p = M3 + ((size_t)col * NT64 + (I * 2 + wm)) * 3;
                p[0] = c1; p[1] = c2; p[2] = c3;
            }
        }
    }
}

// ---------------------------------------------------------------------------
// Kernel 3: exact top-5 per row + per-block loss partial + FUSED final
// reduction via threadfence last-block-done (one fewer launch boundary vs
// the r4 4-kernel file; no co-residency requirement — early blocks exit).
// Ordering: plain partials store -> __threadfence() (device scope) ->
// atomicAdd(done). The block seeing prev==NSEL-1 issues __threadfence()
// then reads all partials (its acquire pairs with every writer's release).
// ---------------------------------------------------------------------------
__global__ __launch_bounds__(256) void select_loss_kernel(const _Float16* __restrict__ xnh,
                                                          const float* __restrict__ M3,
                                                          float* __restrict__ partials,
                                                          unsigned int* __restrict__ done,
                                                          float* __restrict__ out) {
    const int wv = threadIdx.x >> 6, lane = threadIdx.x & 63;
    const int row = blockIdx.x * 4 + wv;
    const float* p = M3 + (size_t)row * NT64 * 3 + lane * 6;
    float a[3], b[3];
    a[0] = p[0]; a[1] = p[1]; a[2] = p[2];
    b[0] = p[3]; b[1] = p[4]; b[2] = p[5];

    float t[KNN];
    {
        float c[KNN] = { a[0], a[1], a[2], -2.f, -2.f };
        const float bb[KNN] = { b[0], b[1], b[2], -2.f, -2.f };
        merge5(c, bb);
        #pragma unroll
        for (int d = 1; d < 64; d <<= 1) {
            float o[KNN];
            #pragma unroll
            for (int k = 0; k < KNN; ++k) o[k] = __shfl_xor(c[k], d, 64);
            merge5(c, o);
        }
        #pragma unroll
        for (int k = 0; k < KNN; ++k) t[k] = c[k];
    }

    // flag tiles whose stored 3rd could hide a missed top-5 value
    const unsigned long long ba = __ballot(a[2] >= t[4]);
    const unsigned long long bb_ = __ballot(b[2] >= t[4]);
    if (ba | bb_) {
        // rebuild the pool top-5 excluding flagged tiles
        const bool fA = (ba >> lane) & 1ull, fB = (bb_ >> lane) & 1ull;
        float c[KNN] = { fA ? -2.f : a[0], fA ? -2.f : a[1], fA ? -2.f : a[2],
                         -2.f, -2.f };
        const float b5[KNN] = { fB ? -2.f : b[0], fB ? -2.f : b[1],
                                fB ? -2.f : b[2], -2.f, -2.f };
        merge5(c, b5);
        #pragma unroll
        for (int d = 1; d < 64; d <<= 1) {
            float o[KNN];
            #pragma unroll
            for (int k = 0; k < KNN; ++k) o[k] = __shfl_xor(c[k], d, 64);
            merge5(c, o);
        }
        #pragma unroll
        for (int k = 0; k < KNN; ++k) t[k] = c[k];

        // exactly recompute each flagged 64-col tile (whole wave, 1 col/lane)
        unsigned long long fl[2] = { ba, bb_ };
        #pragma unroll
        for (int h = 0; h < 2; ++h) {
            unsigned long long m = fl[h];
            while (m) {
                const int l = __ffsll((long long)m) - 1;
                m &= m - 1;
                const int jt2 = 2 * l + h;
                const int col = jt2 * 64 + lane;
                const _Float16* rp = xnh + (size_t)row * DIM;
                const _Float16* cp = xnh + (size_t)col * DIM;
                float d = 0.f;
                for (int k8 = 0; k8 < DIM / 8; ++k8) {
                    const f16x8 rv = *(const f16x8*)(rp + k8 * 8);
                    const f16x8 cv = *(const f16x8*)(cp + k8 * 8);
                    #pragma unroll
                    for (int e = 0; e < 8; ++e)
                        d += (float)rv[e] * (float)cv[e];
                }
                if (col == row) d = -2.f;
                float c2[KNN] = { d, -2.f, -2.f, -2.f, -2.f };
                #pragma unroll
                for (int dd = 1; dd < 64; dd <<= 1) {
                    float o[KNN];
                    #pragma unroll
                    for (int k = 0; k < KNN; ++k) o[k] = __shfl_xor(c2[k], dd, 64);
                    merge5(c2, o);
                }
                merge5(t, c2);
            }
        }
    }

    // loss term: unit vectors -> dist_k = sqrt(2 - 2*dot_k)
    float s = 0.f;
    #pragma unroll
    for (int k = 0; k < KNN; ++k) s += sqrtf(fmaxf(2.f - 2.f * t[k], 0.f));
    const float val = logf(s * (1.f / KNN) + EPSV);

    __shared__ float red[4];
    __shared__ int last;
    if (lane == 0) red[wv] = val;
    __syncthreads();
    if (threadIdx.x == 0) {
        partials[blockIdx.x] = red[0] + red[1] + red[2] + red[3];
        __threadfence();                                   // publish partial
        const unsigned int prev = atomicAdd(done, 1u);     // device-scope
        last = (prev == (unsigned int)(NSEL - 1)) ? 1 : 0;
    }
    __syncthreads();

    if (last) {
        __threadfence();                                   // acquire all partials
        const int tid = threadIdx.x;
        float s2 = 0.f;
        #pragma unroll
        for (int q = 0; q < NSEL / 256; ++q) s2 += partials[tid + q * 256];
        #pragma unroll
        for (int off = 1; off < 64; off <<= 1) s2 += __shfl_xor(s2, off, 64);
        __syncthreads();                 // red[] reuse
        if (lane == 0) red[wv] = s2;
        __syncthreads();
        if (tid == 0)
            *out = -(red[0] + red[1] + red[2] + red[3]) / (float)NROWS;
    }
}

// ---------------------------------------------------------------------------
extern "C" void kernel_launch(void* const* d_in, const int* in_sizes, int n_in,
                              void* d_out, int out_size, void* d_ws, size_t ws_size,
                              hipStream_t stream) {
    const float* x = (const float*)d_in[0];
    float* out = (float*)d_out;
    char* ws = (char*)d_ws;

    _Float16* xnh = (_Float16*)ws;                                     // 8 MB
    float* M3 = (float*)(ws + (size_t)NROWS * DIM * sizeof(_Float16)); // 12.6 MB
    float* partials = M3 + (size_t)NROWS * NT64 * 3;                   // 8 KB
    unsigned int* done = (unsigned int*)(partials + NSEL);             // 4 B

    // zero the completion counter each replay (captured op, graph-legal per r10)
    hipMemsetAsync(done, 0, sizeof(unsigned int), stream);
    norm_kernel<<<NROWS / 4, 256, 0, stream>>>(x, xnh);
    dots_top3_kernel<<<NWORK, 256, 0, stream>>>(xnh, M3);
    select_loss_kernel<<<NSEL, 256, 0, stream>>>(xnh, M3, partials, done, out);
}

// Round 12
// 144.269 us; speedup vs baseline: 2.1908x; 1.2856x over previous
//
#include <hip/hip_runtime.h>
#include <math.h>

// Problem constants (x: [8192, 512] fp32, K=5, eps=1e-8, scalar fp32 loss)
#define NROWS 8192
#define DIM   512
#define KNN   5
#define EPSV  1e-8f

// ============================ SESSION LEDGER ================================
// Best verified config (r4, 144.7us). Findings locked into this file:
//  + XOR chunk swizzle on LDS staging     (r1: SQ_LDS_BANK_CONFLICT 4.26M->0)
//  + XCD-aware super-tile work map        (r2: FETCH 33->23MB, dots -16us)
//  + no same-address atomics anywhere     (r4: -25-30us; r11 re-proved it)
// Falsified (do NOT revisit):
//  - LDS double-buffer w/ syncthreads     (r1: occupancy loss > gain)
//  - BK=64 / wider K-step                 (r3: VGPR/SGPR growth, occ 25->17%)
//  - 8-wave smaller-state tiles           (r5: occ +8pt, dur flat)
//  - direct-from-global fragments         (r6: request-bound scatter, 2x slow)
//  - counted-vmcnt depth-1 and depth-2    (r7/r8: dur flat at ~84-90us)
//  - cooperative kernel launch            (r9: not graph-capturable, no-op)
//  - full persistent fusion               (r10: dots loses inter-block TLP, 2x)
//  - select+reduce fusion via done-counter(r11: 2048 same-addr atomics, +40us)
// dots plateau: ~85us, invariant across occupancy 17-33% and all source-level
// schedule changes. MFMA floor 14us (MfmaUtil 16% x 85us), L2 at 18% of
// ceiling. Total - kernels ~= 45-50us fixed harness overhead (measured r10).
// ============================================================================
#define BM 128
#define BN 128
#define BK 32
#define NT64 (NROWS / 64)      // 128 64-col tiles per row
#define NKS (DIM / BK)         // 16 K-steps
#define NWORK 2080             // 64*65/2 upper-triangular work blocks (= 8*260)
#define NSEL (NROWS / 4)       // select blocks (4 waves, 1 row/wave) = 2048

typedef __attribute__((ext_vector_type(8))) _Float16 f16x8;
typedef __attribute__((ext_vector_type(4))) float    f32x4;

// async global->LDS, 16B per lane (LDS dest must be wave-uniform base + lane*16)
__device__ __forceinline__ void gload16(const _Float16* g, _Float16* l) {
    __builtin_amdgcn_global_load_lds(
        (const __attribute__((address_space(1))) void*)g,
        (__attribute__((address_space(3))) void*)l, 16, 0, 0);
}

__device__ __forceinline__ void cmpswap(float& a, float& b) {
    const float hi = fmaxf(a, b), lo = fminf(a, b);
    a = hi; b = lo;
}

// merge two sorted-descending 5-lists -> top-5 (into a).
__device__ __forceinline__ void merge5(float a[KNN], const float b[KNN]) {
    const float c0 = fmaxf(a[0], b[0]);
    const float c1 = fmaxf(fmaxf(a[1], b[1]), fminf(a[0], b[0]));
    const float c2 = fmaxf(fmaxf(a[2], b[2]),
                           fmaxf(fminf(a[0], b[1]), fminf(a[1], b[0])));
    const float c3 = fmaxf(fmaxf(a[3], b[3]),
                           fmaxf(fminf(a[0], b[2]),
                                 fmaxf(fminf(a[1], b[1]), fminf(a[2], b[0]))));
    const float c4 = fmaxf(fmaxf(a[4], b[4]),
                           fmaxf(fmaxf(fminf(a[0], b[3]), fminf(a[1], b[2])),
                                 fmaxf(fminf(a[2], b[1]), fminf(a[3], b[0]))));
    a[0] = c0; a[1] = c1; a[2] = c2; a[3] = c3; a[4] = c4;
}

// ---------------------------------------------------------------------------
// Kernel 1: row-normalize x (fp32) -> xn (f16). One WAVE per row, 16B stores.
// ---------------------------------------------------------------------------
__global__ __launch_bounds__(256) void norm_kernel(const float* __restrict__ x,
                                                   _Float16* __restrict__ xnh) {
    const int wv = threadIdx.x >> 6, lane = threadIdx.x & 63;
    const int row = blockIdx.x * 4 + wv;
    const float4* xr = (const float4*)(x + (size_t)row * DIM) + lane * 2;
    const float4 a = xr[0];
    const float4 b = xr[1];
    float s = a.x * a.x + a.y * a.y + a.z * a.z + a.w * a.w
            + b.x * b.x + b.y * b.y + b.z * b.z + b.w * b.w;
    #pragma unroll
    for (int off = 1; off < 64; off <<= 1) s += __shfl_xor(s, off, 64);
    const float inv = 1.0f / sqrtf(s);
    const f16x8 h = { (_Float16)(a.x * inv), (_Float16)(a.y * inv),
                      (_Float16)(a.z * inv), (_Float16)(a.w * inv),
                      (_Float16)(b.x * inv), (_Float16)(b.y * inv),
                      (_Float16)(b.z * inv), (_Float16)(b.w * inv) };
    *(f16x8*)(xnh + (size_t)row * DIM + lane * 8) = h;
}

// ---------------------------------------------------------------------------
// Kernel 2: TRIANGULAR Gram-tile GEMM + per-(row, 64-col-tile) top-3.
// r4-EXACT (best verified; see session ledger above).
// ---------------------------------------------------------------------------
__global__ __launch_bounds__(256) void dots_top3_kernel(const _Float16* __restrict__ xnh,
                                                        float* __restrict__ M3) {
    // ---- work-index decode: launch b -> XCD-contiguous work item w -> (I,J)
    // XCD x = b&7 gets slots w in [x*260, (x+1)*260); work enumerated over
    // super-tiles (SI,SJ>=SI) of 8x8 tiles; diag super-tiles hold the 36
    // upper-tri pairs, off-diag hold all 64. Totals: 8*36 + 28*64 = 2080.
    int I, J;
    {
        int rem = (int)(blockIdx.x & 7) * (NWORK / 8) + (int)(blockIdx.x >> 3);
        int found = 0;
        for (int SI = 0; SI < 8 && !found; ++SI) {
            for (int SJ = SI; SJ < 8 && !found; ++SJ) {
                const int sz = (SI == SJ) ? 36 : 64;
                if (rem < sz) {
                    if (SI == SJ) {
                        int i = 0, r2 = rem;
                        while (r2 >= 8 - i) { r2 -= 8 - i; ++i; }
                        I = SI * 8 + i;
                        J = SJ * 8 + i + r2;
                    } else {
                        I = SI * 8 + (rem >> 3);
                        J = SJ * 8 + (rem & 7);
                    }
                    found = 1;
                } else {
                    rem -= sz;
                }
            }
        }
    }

    __shared__ __align__(16) _Float16 As[BM * BK];   // 8 KB
    __shared__ __align__(16) _Float16 Bs[BN * BK];   // 8 KB

    const int tid    = threadIdx.x;
    const int lane   = tid & 63;
    const int wv     = tid >> 6;
    const int wm     = wv >> 1;          // wave row half (0..1)
    const int wn     = wv & 1;           // wave col half (0..1)
    const int m_lane = lane & 15;        // MFMA: m (A) / n (B) / col (C)
    const int quad   = lane >> 4;        // MFMA: k-chunk (A,B) / row-group (C)

    const int i0 = I * BM;
    const int j0 = J * BN;

    // lane (quad, m_lane) owns row rowlocal (its (m,i) = (m_lane>>2, m_lane&3))
    const int rowlocal = (m_lane >> 2) * 16 + quad * 4 + (m_lane & 3);
    const int myrow    = i0 + wm * 64 + rowlocal;

    // fragment-read chunk swizzle: (row>>1)&3 == (m_lane>>1)&3 for every m, wm
    const int rchunk = (quad ^ ((m_lane >> 1) & 3)) * 8;

    f32x4 acc[4][4];
    #pragma unroll
    for (int m = 0; m < 4; ++m)
        #pragma unroll
        for (int n = 0; n < 4; ++n)
            acc[m][n] = (f32x4){0.f, 0.f, 0.f, 0.f};

    for (int ks = 0; ks < NKS; ++ks) {
        const int k0 = ks * BK;
        // LDS slot s (row r, chunk kk) receives global chunk kk ^ ((r>>1)&3)
        // (involution; fragment read applies the same XOR via rchunk).
        #pragma unroll
        for (int q = 0; q < 2; ++q) {
            const int s  = tid + q * 256;
            const int r  = s >> 2;
            const int kg = (s & 3) ^ ((s >> 3) & 3);
            gload16(xnh + (size_t)(i0 + r) * DIM + k0 + kg * 8, As + s * 8);
            gload16(xnh + (size_t)(j0 + r) * DIM + k0 + kg * 8, Bs + s * 8);
        }
        __syncthreads();

        f16x8 af[4], bf[4];
        #pragma unroll
        for (int m = 0; m < 4; ++m)
            af[m] = *(const f16x8*)(As + (wm * 64 + m * 16 + m_lane) * BK + rchunk);
        #pragma unroll
        for (int n = 0; n < 4; ++n)
            bf[n] = *(const f16x8*)(Bs + (wn * 64 + n * 16 + m_lane) * BK + rchunk);
        #pragma unroll
        for (int m = 0; m < 4; ++m)
            #pragma unroll
            for (int n = 0; n < 4; ++n)
                acc[m][n] = __builtin_amdgcn_mfma_f32_16x16x32_f16(af[m], bf[n], acc[m][n], 0, 0, 0);
        __syncthreads();
    }

    // diagonal mask: self-dot only when I==J && wm==wn && m==n.
    const bool diag = (I == J) && (wm == wn);
    #pragma unroll
    for (int m = 0; m < 4; ++m)
        #pragma unroll
        for (int i = 0; i < 4; ++i)
            acc[m][m][i] = (diag && (quad * 4 + i) == m_lane) ? -2.f : acc[m][m][i];

    // ---- row-side: per (m,i), top-3 of this row's 64 cols (butterfly) ----
    float g1 = -2.f, g2 = -2.f, g3 = -2.f;
    #pragma unroll
    for (int m = 0; m < 4; ++m) {
        #pragma unroll
        for (int i = 0; i < 4; ++i) {
            float v0 = acc[m][0][i], v1 = acc[m][1][i];
            float v2 = acc[m][2][i], v3 = acc[m][3][i];
            cmpswap(v0, v1); cmpswap(v2, v3);
            cmpswap(v0, v2); cmpswap(v1, v3);
            cmpswap(v1, v2);                     // v0>=v1>=v2 (>=v3, dropped)
            float a1 = v0, a2 = v1, a3 = v2;
            #pragma unroll
            for (int d = 1; d < 16; d <<= 1) {
                const float b1 = __shfl_xor(a1, d, 64);
                const float b2 = __shfl_xor(a2, d, 64);
                const float b3 = __shfl_xor(a3, d, 64);
                const float n1 = fmaxf(a1, b1);
                const float n2 = fmaxf(fminf(a1, b1), fmaxf(a2, b2));
                const float n3 = fmaxf(fmaxf(a3, b3),
                                       fmaxf(fminf(a1, b2), fminf(a2, b1)));
                a1 = n1; a2 = n2; a3 = n3;
            }
            const bool own = (m_lane == m * 4 + i);
            g1 = own ? a1 : g1; g2 = own ? a2 : g2; g3 = own ? a3 : g3;
        }
    }
    {
        float* p = M3 + ((size_t)myrow * NT64 + (J * 2 + wn)) * 3;
        p[0] = g1; p[1] = g2; p[2] = g3;
    }

    // ---- col-side (I != J): per n, top-3 of this col's 64 rows ----
    // lane-local insert3 over (m,i) [16 vals], then butterfly over quad
    // (lane bits 4,5 -> shfl_xor 16, 32). Column = j0 + wn*64 + n*16 + m_lane;
    // its 64-row range is tile index I*2 + wm.
    if (I != J) {
        #pragma unroll
        for (int n = 0; n < 4; ++n) {
            float c1 = -2.f, c2 = -2.f, c3 = -2.f;
            #pragma unroll
            for (int m = 0; m < 4; ++m)
                #pragma unroll
                for (int i = 0; i < 4; ++i) {
                    const float v  = acc[m][n][i];
                    const float u1 = fminf(c1, v);
                    c1 = fmaxf(c1, v);
                    const float u2 = fminf(c2, u1);
                    c2 = fmaxf(c2, u1);
                    c3 = fmaxf(c3, u2);
                }
            #pragma unroll
            for (int d = 16; d < 64; d <<= 1) {
                const float b1 = __shfl_xor(c1, d, 64);
                const float b2 = __shfl_xor(c2, d, 64);
                const float b3 = __shfl_xor(c3, d, 64);
                const float n2 = fmaxf(fminf(c1, b1), fmaxf(c2, b2));
                const float n3 = fmaxf(fmaxf(c3, b3),
                                       fmaxf(fminf(c1, b2), fminf(c2, b1)));
                c1 = fmaxf(c1, b1); c2 = n2; c3 = n3;
            }
            if (quad == 0) {
                const int col = j0 + wn * 64 + n * 16 + m_lane;
                float* p = M3 + ((size_t)col * NT64 + (I * 2 + wm)) * 3;
                p[0] = c1; p[1] = c2; p[2] = c3;
            }
        }
    }
}

// ---------------------------------------------------------------------------
// Kernel 3: exact top-5 per row from the 128 stored triples + per-block
// partial of the loss sum. NO single-address atomics (r4/r11 lesson).
// ---------------------------------------------------------------------------
__global__ __launch_bounds__(256) void select_loss_kernel(const _Float16* __restrict__ xnh,
                                                          const float* __restrict__ M3,
                                                          float* __restrict__ partials) {
    const int wv = threadIdx.x >> 6, lane = threadIdx.x & 63;
    const int row = blockIdx.x * 4 + wv;
    const float* p = M3 + (size_t)row * NT64 * 3 + lane * 6;
    float a[3], b[3];
    a[0] = p[0]; a[1] = p[1]; a[2] = p[2];
    b[0] = p[3]; b[1] = p[4]; b[2] = p[5];

    float t[KNN];
    {
        float c[KNN] = { a[0], a[1], a[2], -2.f, -2.f };
        const float bb[KNN] = { b[0], b[1], b[2], -2.f, -2.f };
        merge5(c, bb);
        #pragma unroll
        for (int d = 1; d < 64; d <<= 1) {
            float o[KNN];
            #pragma unroll
            for (int k = 0; k < KNN; ++k) o[k] = __shfl_xor(c[k], d, 64);
            merge5(c, o);
        }
        #pragma unroll
        for (int k = 0; k < KNN; ++k) t[k] = c[k];
    }

    // flag tiles whose stored 3rd could hide a missed top-5 value
    const unsigned long long ba = __ballot(a[2] >= t[4]);
    const unsigned long long bb_ = __ballot(b[2] >= t[4]);
    if (ba | bb_) {
        // rebuild the pool top-5 excluding flagged tiles
        const bool fA = (ba >> lane) & 1ull, fB = (bb_ >> lane) & 1ull;
        float c[KNN] = { fA ? -2.f : a[0], fA ? -2.f : a[1], fA ? -2.f : a[2],
                         -2.f, -2.f };
        const float b5[KNN] = { fB ? -2.f : b[0], fB ? -2.f : b[1],
                                fB ? -2.f : b[2], -2.f, -2.f };
        merge5(c, b5);
        #pragma unroll
        for (int d = 1; d < 64; d <<= 1) {
            float o[KNN];
            #pragma unroll
            for (int k = 0; k < KNN; ++k) o[k] = __shfl_xor(c[k], d, 64);
            merge5(c, o);
        }
        #pragma unroll
        for (int k = 0; k < KNN; ++k) t[k] = c[k];

        // exactly recompute each flagged 64-col tile (whole wave, 1 col/lane)
        unsigned long long fl[2] = { ba, bb_ };
        #pragma unroll
        for (int h = 0; h < 2; ++h) {
            unsigned long long m = fl[h];
            while (m) {
                const int l = __ffsll((long long)m) - 1;
                m &= m - 1;
                const int jt2 = 2 * l + h;
                const int col = jt2 * 64 + lane;
                const _Float16* rp = xnh + (size_t)row * DIM;
                const _Float16* cp = xnh + (size_t)col * DIM;
                float d = 0.f;
                for (int k8 = 0; k8 < DIM / 8; ++k8) {
                    const f16x8 rv = *(const f16x8*)(rp + k8 * 8);
                    const f16x8 cv = *(const f16x8*)(cp + k8 * 8);
                    #pragma unroll
                    for (int e = 0; e < 8; ++e)
                        d += (float)rv[e] * (float)cv[e];
                }
                if (col == row) d = -2.f;
                float c2[KNN] = { d, -2.f, -2.f, -2.f, -2.f };
                #pragma unroll
                for (int dd = 1; dd < 64; dd <<= 1) {
                    float o[KNN];
                    #pragma unroll
                    for (int k = 0; k < KNN; ++k) o[k] = __shfl_xor(c2[k], dd, 64);
                    merge5(c2, o);
                }
                merge5(t, c2);
            }
        }
    }

    // loss term: unit vectors -> dist_k = sqrt(2 - 2*dot_k)
    float s = 0.f;
    #pragma unroll
    for (int k = 0; k < KNN; ++k) s += sqrtf(fmaxf(2.f - 2.f * t[k], 0.f));
    const float val = logf(s * (1.f / KNN) + EPSV);

    __shared__ float red[4];
    if (lane == 0) red[wv] = val;
    __syncthreads();
    if (threadIdx.x == 0)
        partials[blockIdx.x] = red[0] + red[1] + red[2] + red[3];
}

// ---------------------------------------------------------------------------
// Kernel 4: reduce the 2048 per-block partials -> loss. One block.
// ---------------------------------------------------------------------------
__global__ __launch_bounds__(256) void reduce_kernel(const float* __restrict__ partials,
                                                     float* __restrict__ out) {
    const int tid = threadIdx.x, lane = tid & 63, wv = tid >> 6;
    float s = 0.f;
    #pragma unroll
    for (int q = 0; q < NSEL / 256; ++q) s += partials[tid + q * 256];
    #pragma unroll
    for (int off = 1; off < 64; off <<= 1) s += __shfl_xor(s, off, 64);
    __shared__ float red[4];
    if (lane == 0) red[wv] = s;
    __syncthreads();
    if (tid == 0)
        *out = -(red[0] + red[1] + red[2] + red[3]) / (float)NROWS;
}

// ---------------------------------------------------------------------------
extern "C" void kernel_launch(void* const* d_in, const int* in_sizes, int n_in,
                              void* d_out, int out_size, void* d_ws, size_t ws_size,
                              hipStream_t stream) {
    const float* x = (const float*)d_in[0];
    float* out = (float*)d_out;
    char* ws = (char*)d_ws;

    _Float16* xnh = (_Float16*)ws;                                     // 8 MB
    float* M3 = (float*)(ws + (size_t)NROWS * DIM * sizeof(_Float16)); // 12.6 MB
    float* partials = M3 + (size_t)NROWS * NT64 * 3;                   // 8 KB

    norm_kernel<<<NROWS / 4, 256, 0, stream>>>(x, xnh);
    dots_top3_kernel<<<NWORK, 256, 0, stream>>>(xnh, M3);
    select_loss_kernel<<<NSEL, 256, 0, stream>>>(xnh, M3, partials);
    reduce_kernel<<<1, 256, 0, stream>>>(partials, out);
}